// Round 9
// baseline (208.843 us; speedup 1.0000x reference)
//
#include <hip/hip_runtime.h>
#include <hip/hip_bf16.h>

#define SEQ 64
#define DIM 512
#define VOCAB 300
#define LDQ 516   // ushort row stride for qkv LDS: 1032B rows (8B-aligned). 8-row quad stride
                  // = 2064 dwords = 16 mod 32 banks -> 2-way aliasing only (free).
#define LDSC 72   // ushort row stride for scores (144B rows, 16B-aligned)

typedef __attribute__((ext_vector_type(8))) short short8;   // 8 bf16 (MFMA A/B frag)
typedef __attribute__((ext_vector_type(4))) float floatx4;  // MFMA C/D frag; also nt-store vector

static __device__ inline unsigned short f2bf(float x) {
    __hip_bfloat16 t = __float2bfloat16(x);
    return *reinterpret_cast<unsigned short*>(&t);
}

// load 8 bf16 from an 8B-aligned LDS address (two uint2 -> ds_read2_b64)
static __device__ inline short8 ld8(const unsigned short* p) {
    union { short8 s; uint2 u[2]; } r;
    r.u[0] = *(const uint2*)p;
    r.u[1] = *(const uint2*)(p + 4);
    return r.s;
}

// ---- prep: P = emb @ Qdense (300x512 @ 512x512, bf16 out).
// One 16x16 output tile per WAVE: grid (32 n-tiles) x (19 m-tiles), 64 thr.
__global__ __launch_bounds__(64) void proj_kernel(
    const float* __restrict__ emb,   // fp32 [300][512]
    const float* __restrict__ Q,     // fp32 [512][512], row-major [k][n]
    __hip_bfloat16* __restrict__ P)  // bf16 [300][512]
{
    const int lane = threadIdx.x & 63;
    const int quad = lane >> 4;
    const int l16 = lane & 15;
    const int nt = blockIdx.x;       // 0..31  (column tile)
    const int mt = blockIdx.y;       // 0..18  (row tile; last is partial)
    const int n = nt * 16 + l16;
    const int vrow = mt * 16 + l16;  // A-operand row this lane loads

    floatx4 acc = {};
#pragma unroll 4
    for (int k0 = 0; k0 < DIM; k0 += 32) {
        float4 x0 = {0, 0, 0, 0}, x1 = {0, 0, 0, 0};
        if (vrow < VOCAB) {
            x0 = *(const float4*)(emb + (size_t)vrow * DIM + k0 + quad * 8);
            x1 = *(const float4*)(emb + (size_t)vrow * DIM + k0 + quad * 8 + 4);
        }
        union { short8 s; unsigned short h[8]; } ua;
        ua.h[0] = f2bf(x0.x); ua.h[1] = f2bf(x0.y); ua.h[2] = f2bf(x0.z); ua.h[3] = f2bf(x0.w);
        ua.h[4] = f2bf(x1.x); ua.h[5] = f2bf(x1.y); ua.h[6] = f2bf(x1.z); ua.h[7] = f2bf(x1.w);

        union { short8 s; unsigned short h[8]; } ub;
#pragma unroll
        for (int j = 0; j < 8; j++)
            ub.h[j] = f2bf(Q[(size_t)(k0 + quad * 8 + j) * DIM + n]);

        acc = __builtin_amdgcn_mfma_f32_16x16x32_bf16(ua.s, ub.s, acc, 0, 0, 0);
    }
#pragma unroll
    for (int r = 0; r < 4; r++) {
        int v = mt * 16 + quad * 4 + r;
        if (v < VOCAB) P[(size_t)v * DIM + n] = __float2bfloat16(acc[r]);
    }
}

// ---- main fused kernel: one block per batch, 8 waves, 2 blocks/CU.
// 2 barriers total. Phase C computes encoded^T (operand-swapped MFMA) so each
// lane's accumulator quad IS a float4 of consecutive out columns -> register
// epilogue, no LDS round trip. Bit-identical numerics to the previous version
// (same products, same k-order).
__global__ __launch_bounds__(512, 4) void fused_attn_kernel(
    const int* __restrict__ ids_en,
    const int* __restrict__ ids_fr,
    const float* __restrict__ emb,            // fp32 [300][512] (epilogue residual)
    const __hip_bfloat16* __restrict__ P,     // bf16 [300][512] = emb @ W
    float* __restrict__ out)                  // fp32 [B][64][512]
{
    __shared__ __align__(16) unsigned short qk[SEQ * LDQ];   // qkv rows (66048 B)
    __shared__ __align__(16) unsigned short sc[SEQ * LDSC];  // scores bf16 (9216 B)

    const int b = blockIdx.x;
    const int tid = threadIdx.x;
    const int lane = tid & 63;
    const int w = tid >> 6;
    const int quad = lane >> 4;
    const int l16 = lane & 15;
    const int wv = __builtin_amdgcn_readfirstlane(w);  // SGPR wave id

    // ---- stage qkv = P[ids_fr] into LDS. Row ids are wave-uniform scalar
    // loads (no LDS, no barrier); T14 load/write split on the row gathers.
    {
        int rid[8];
#pragma unroll
        for (int i = 0; i < 8; i++)
            rid[i] = ids_fr[b * SEQ + i * 8 + wv];       // s_load (uniform addr)
        uint4 v[8];
#pragma unroll
        for (int i = 0; i < 8; i++)
            v[i] = *(const uint4*)(P + (size_t)rid[i] * DIM + lane * 8);
#pragma unroll
        for (int i = 0; i < 8; i++) {
            unsigned short* dst = qk + (i * 8 + wv) * LDQ + lane * 8;
            *(uint2*)dst = make_uint2(v[i].x, v[i].y);
            *(uint2*)(dst + 4) = make_uint2(v[i].z, v[i].w);
        }
    }

    // early per-lane loads for later phases (latency hides under staging/B)
    const int t0 = w * 2;
    const int qi = w >> 1;
    const int ki0 = t0 & 3, ki1 = (t0 + 1) & 3;
    float mk0 = (ids_fr[b * SEQ + ki0 * 16 + l16] != 0) ? 1.0f : 0.0f;
    float mk1 = (ids_fr[b * SEQ + ki1 * 16 + l16] != 0) ? 1.0f : 0.0f;
    int idE[4];
#pragma unroll
    for (int q = 0; q < 4; q++)
        idE[q] = ids_en[b * SEQ + q * 16 + l16];

    __syncthreads();  // barrier 1: staging visible

    // ---- Phase B: scores = (qkv @ qkv^T) * mask[k]  (16 16x16 tiles, 2/wave, K=512) ----
    short8 bbr[2][4];  // Phase C A-fragments (qkv^T), hoisted
    {
        floatx4 accS[2] = {};
        for (int k0 = 0; k0 < DIM; k0 += 32) {
            short8 aa = ld8(qk + (qi * 16 + l16) * LDQ + k0 + quad * 8);
            short8 b0 = ld8(qk + (ki0 * 16 + l16) * LDQ + k0 + quad * 8);
            accS[0] = __builtin_amdgcn_mfma_f32_16x16x32_bf16(aa, b0, accS[0], 0, 0, 0);
            short8 b1 = ld8(qk + (ki1 * 16 + l16) * LDQ + k0 + quad * 8);
            accS[1] = __builtin_amdgcn_mfma_f32_16x16x32_bf16(aa, b1, accS[1], 0, 0, 0);
        }

        // Phase C A-fragment gather: bbr[kx][ni][j] = qkv^T[n][k] column reads
#pragma unroll
        for (int kx = 0; kx < 2; kx++)
#pragma unroll
            for (int ni = 0; ni < 4; ni++)
#pragma unroll
                for (int j = 0; j < 8; j++)
                    ((unsigned short*)&bbr[kx][ni])[j] =
                        qk[(kx * 32 + quad * 8 + j) * LDQ + w * 64 + ni * 16 + l16];

        // sc writes (masked)
#pragma unroll
        for (int r = 0; r < 4; r++) {
            int row = qi * 16 + quad * 4 + r;
            sc[row * LDSC + ki0 * 16 + l16] = f2bf(accS[0][r] * mk0);
            sc[row * LDSC + ki1 * 16 + l16] = f2bf(accS[1][r] * mk1);
        }
    }
    __syncthreads();  // barrier 2: scores visible

    // ---- Phase C (transposed) + register epilogue, two passes of 32 m-rows.
    // acc[mi][ni] holds out[m = p*32+mi*16+l16][cols w*64+ni*16+quad*4 .. +3].
    const size_t out_base = (size_t)b * SEQ * DIM;
#pragma unroll
    for (int p = 0; p < 2; p++) {
        // issue residual loads first; latency hides under the MFMAs
        floatx4 e[2][4];
#pragma unroll
        for (int mi = 0; mi < 2; mi++)
#pragma unroll
            for (int ni = 0; ni < 4; ni++)
                e[mi][ni] = *(const floatx4*)(
                    emb + (size_t)idE[p * 2 + mi] * DIM + w * 64 + ni * 16 + quad * 4);

        floatx4 acc[2][4] = {};
#pragma unroll
        for (int kx = 0; kx < 2; kx++) {
            short8 bf_[2];  // B-fragments (scores^T) — same ld8 pattern as before
#pragma unroll
            for (int mi = 0; mi < 2; mi++)
                bf_[mi] = *(const short8*)(
                    sc + (p * 32 + mi * 16 + l16) * LDSC + kx * 32 + quad * 8);
#pragma unroll
            for (int ni = 0; ni < 4; ni++)
#pragma unroll
                for (int mi = 0; mi < 2; mi++)
                    acc[mi][ni] = __builtin_amdgcn_mfma_f32_16x16x32_bf16(
                        bbr[kx][ni], bf_[mi], acc[mi][ni], 0, 0, 0);
        }

#pragma unroll
        for (int mi = 0; mi < 2; mi++) {
            int m = p * 32 + mi * 16 + l16;
#pragma unroll
            for (int ni = 0; ni < 4; ni++) {
                floatx4 o = e[mi][ni] + acc[mi][ni];
                __builtin_nontemporal_store(
                    o, (floatx4*)(out + out_base + (size_t)m * DIM + w * 64 + ni * 16 + quad * 4));
            }
        }
    }
}

extern "C" void kernel_launch(void* const* d_in, const int* in_sizes, int n_in,
                              void* d_out, int out_size, void* d_ws, size_t ws_size,
                              hipStream_t stream) {
    const int* ids_en = (const int*)d_in[0];
    const int* ids_fr = (const int*)d_in[1];
    const float* emb  = (const float*)d_in[2];
    const float* Qd   = (const float*)d_in[3];
    float* out = (float*)d_out;

    const int B = in_sizes[0] / SEQ;  // 1024

    __hip_bfloat16* P = (__hip_bfloat16*)d_ws;  // 300*512*2 = 307200 B

    proj_kernel<<<dim3(32, 19), 64, 0, stream>>>(emb, Qd, P);
    fused_attn_kernel<<<B, 512, 0, stream>>>(ids_en, ids_fr, emb, P, out);
}

// Round 10
// 181.285 us; speedup vs baseline: 1.1520x; 1.1520x over previous
//
#include <hip/hip_runtime.h>
#include <hip/hip_bf16.h>

#define SEQ 64
#define DIM 512
#define VOCAB 300
#define LDQ 516   // ushort row stride for qkv LDS: 1032B rows (8B-aligned). 8-row quad stride
                  // = 2064 dwords = 16 mod 32 banks -> 2-way aliasing only (free).
#define LDSC 72   // ushort row stride for scores (144B rows, 16B-aligned)

typedef __attribute__((ext_vector_type(8))) short short8;   // 8 bf16 (MFMA A/B frag)
typedef __attribute__((ext_vector_type(4))) float floatx4;  // MFMA C/D frag

static __device__ inline unsigned short f2bf(float x) {
    __hip_bfloat16 t = __float2bfloat16(x);
    return *reinterpret_cast<unsigned short*>(&t);
}

// load 8 bf16 from an 8B-aligned LDS address (two uint2 -> ds_read2_b64)
static __device__ inline short8 ld8(const unsigned short* p) {
    union { short8 s; uint2 u[2]; } r;
    r.u[0] = *(const uint2*)p;
    r.u[1] = *(const uint2*)(p + 4);
    return r.s;
}

// ---- prep: P = emb @ Qdense (300x512 @ 512x512, bf16 out).
// One 16x16 output tile per WAVE: grid (32 n-tiles) x (19 m-tiles), 64 thr.
__global__ __launch_bounds__(64) void proj_kernel(
    const float* __restrict__ emb,   // fp32 [300][512]
    const float* __restrict__ Q,     // fp32 [512][512], row-major [k][n]
    __hip_bfloat16* __restrict__ P)  // bf16 [300][512]
{
    const int lane = threadIdx.x & 63;
    const int quad = lane >> 4;
    const int l16 = lane & 15;
    const int nt = blockIdx.x;       // 0..31  (column tile)
    const int mt = blockIdx.y;       // 0..18  (row tile; last is partial)
    const int n = nt * 16 + l16;
    const int vrow = mt * 16 + l16;  // A-operand row this lane loads

    floatx4 acc = {};
#pragma unroll 4
    for (int k0 = 0; k0 < DIM; k0 += 32) {
        float4 x0 = {0, 0, 0, 0}, x1 = {0, 0, 0, 0};
        if (vrow < VOCAB) {
            x0 = *(const float4*)(emb + (size_t)vrow * DIM + k0 + quad * 8);
            x1 = *(const float4*)(emb + (size_t)vrow * DIM + k0 + quad * 8 + 4);
        }
        union { short8 s; unsigned short h[8]; } ua;
        ua.h[0] = f2bf(x0.x); ua.h[1] = f2bf(x0.y); ua.h[2] = f2bf(x0.z); ua.h[3] = f2bf(x0.w);
        ua.h[4] = f2bf(x1.x); ua.h[5] = f2bf(x1.y); ua.h[6] = f2bf(x1.z); ua.h[7] = f2bf(x1.w);

        union { short8 s; unsigned short h[8]; } ub;
#pragma unroll
        for (int j = 0; j < 8; j++)
            ub.h[j] = f2bf(Q[(size_t)(k0 + quad * 8 + j) * DIM + n]);

        acc = __builtin_amdgcn_mfma_f32_16x16x32_bf16(ua.s, ub.s, acc, 0, 0, 0);
    }
#pragma unroll
    for (int r = 0; r < 4; r++) {
        int v = mt * 16 + quad * 4 + r;
        if (v < VOCAB) P[(size_t)v * DIM + n] = __float2bfloat16(acc[r]);
    }
}

// ---- main fused kernel: one block per batch, 8 waves, 2 blocks/CU.
// 2 barriers total. Phase C computes encoded^T (operand-swapped MFMA) so each
// lane's accumulator quad IS a float4 of consecutive out columns -> register
// epilogue. Stores are PLAIN (not nontemporal): the wave-level pattern is 16
// scattered 64B row-segments, and L2 write-back must aggregate them into full
// lines (nt bypassed L2 and forced ~64B HBM transactions -> R9's +40us).
__global__ __launch_bounds__(512, 4) void fused_attn_kernel(
    const int* __restrict__ ids_en,
    const int* __restrict__ ids_fr,
    const float* __restrict__ emb,            // fp32 [300][512] (epilogue residual)
    const __hip_bfloat16* __restrict__ P,     // bf16 [300][512] = emb @ W
    float* __restrict__ out)                  // fp32 [B][64][512]
{
    __shared__ __align__(16) unsigned short qk[SEQ * LDQ];   // qkv rows (66048 B)
    __shared__ __align__(16) unsigned short sc[SEQ * LDSC];  // scores bf16 (9216 B)

    const int b = blockIdx.x;
    const int tid = threadIdx.x;
    const int lane = tid & 63;
    const int w = tid >> 6;
    const int quad = lane >> 4;
    const int l16 = lane & 15;
    const int wv = __builtin_amdgcn_readfirstlane(w);  // SGPR wave id

    // ---- stage qkv = P[ids_fr] into LDS. Row ids are wave-uniform scalar
    // loads (no LDS, no barrier); T14 load/write split on the row gathers.
    {
        int rid[8];
#pragma unroll
        for (int i = 0; i < 8; i++)
            rid[i] = ids_fr[b * SEQ + i * 8 + wv];       // s_load (uniform addr)
        uint4 v[8];
#pragma unroll
        for (int i = 0; i < 8; i++)
            v[i] = *(const uint4*)(P + (size_t)rid[i] * DIM + lane * 8);
#pragma unroll
        for (int i = 0; i < 8; i++) {
            unsigned short* dst = qk + (i * 8 + wv) * LDQ + lane * 8;
            *(uint2*)dst = make_uint2(v[i].x, v[i].y);
            *(uint2*)(dst + 4) = make_uint2(v[i].z, v[i].w);
        }
    }

    // early per-lane loads for later phases (latency hides under staging/B)
    const int t0 = w * 2;
    const int qi = w >> 1;
    const int ki0 = t0 & 3, ki1 = (t0 + 1) & 3;
    float mk0 = (ids_fr[b * SEQ + ki0 * 16 + l16] != 0) ? 1.0f : 0.0f;
    float mk1 = (ids_fr[b * SEQ + ki1 * 16 + l16] != 0) ? 1.0f : 0.0f;
    int idE[4];
#pragma unroll
    for (int q = 0; q < 4; q++)
        idE[q] = ids_en[b * SEQ + q * 16 + l16];

    __syncthreads();  // barrier 1: staging visible

    // ---- Phase B: scores = (qkv @ qkv^T) * mask[k]  (16 16x16 tiles, 2/wave, K=512) ----
    short8 bbr[2][4];  // Phase C A-fragments (qkv^T), hoisted
    {
        floatx4 accS[2] = {};
        for (int k0 = 0; k0 < DIM; k0 += 32) {
            short8 aa = ld8(qk + (qi * 16 + l16) * LDQ + k0 + quad * 8);
            short8 b0 = ld8(qk + (ki0 * 16 + l16) * LDQ + k0 + quad * 8);
            accS[0] = __builtin_amdgcn_mfma_f32_16x16x32_bf16(aa, b0, accS[0], 0, 0, 0);
            short8 b1 = ld8(qk + (ki1 * 16 + l16) * LDQ + k0 + quad * 8);
            accS[1] = __builtin_amdgcn_mfma_f32_16x16x32_bf16(aa, b1, accS[1], 0, 0, 0);
        }

        // Phase C A-fragment gather: bbr[kx][ni][j] = qkv^T[n][k] column reads
#pragma unroll
        for (int kx = 0; kx < 2; kx++)
#pragma unroll
            for (int ni = 0; ni < 4; ni++)
#pragma unroll
                for (int j = 0; j < 8; j++)
                    ((unsigned short*)&bbr[kx][ni])[j] =
                        qk[(kx * 32 + quad * 8 + j) * LDQ + w * 64 + ni * 16 + l16];

        // sc writes (masked)
#pragma unroll
        for (int r = 0; r < 4; r++) {
            int row = qi * 16 + quad * 4 + r;
            sc[row * LDSC + ki0 * 16 + l16] = f2bf(accS[0][r] * mk0);
            sc[row * LDSC + ki1 * 16 + l16] = f2bf(accS[1][r] * mk1);
        }
    }
    __syncthreads();  // barrier 2: scores visible

    // ---- Phase C (transposed) + register epilogue, two passes of 32 m-rows.
    // acc[mi][ni] holds out[m = p*32+mi*16+l16][cols w*64+ni*16+quad*4 .. +3].
    // Residual loads issued per-mi just before that mi's stores (peak VGPR ~90,
    // well under the 128 cap -> no spill risk).
    const size_t out_base = (size_t)b * SEQ * DIM;
#pragma unroll
    for (int p = 0; p < 2; p++) {
        floatx4 acc[2][4] = {};
#pragma unroll
        for (int kx = 0; kx < 2; kx++) {
            short8 bf_[2];  // B-fragments (scores^T)
#pragma unroll
            for (int mi = 0; mi < 2; mi++)
                bf_[mi] = *(const short8*)(
                    sc + (p * 32 + mi * 16 + l16) * LDSC + kx * 32 + quad * 8);
#pragma unroll
            for (int ni = 0; ni < 4; ni++)
#pragma unroll
                for (int mi = 0; mi < 2; mi++)
                    acc[mi][ni] = __builtin_amdgcn_mfma_f32_16x16x32_bf16(
                        bbr[kx][ni], bf_[mi], acc[mi][ni], 0, 0, 0);
        }

#pragma unroll
        for (int mi = 0; mi < 2; mi++) {
            int m = p * 32 + mi * 16 + l16;
            floatx4 e[4];
#pragma unroll
            for (int ni = 0; ni < 4; ni++)
                e[ni] = *(const floatx4*)(
                    emb + (size_t)idE[p * 2 + mi] * DIM + w * 64 + ni * 16 + quad * 4);
#pragma unroll
            for (int ni = 0; ni < 4; ni++) {
                floatx4 o = e[ni] + acc[mi][ni];
                *(floatx4*)(out + out_base + (size_t)m * DIM + w * 64 + ni * 16 + quad * 4) = o;
            }
        }
    }
}

extern "C" void kernel_launch(void* const* d_in, const int* in_sizes, int n_in,
                              void* d_out, int out_size, void* d_ws, size_t ws_size,
                              hipStream_t stream) {
    const int* ids_en = (const int*)d_in[0];
    const int* ids_fr = (const int*)d_in[1];
    const float* emb  = (const float*)d_in[2];
    const float* Qd   = (const float*)d_in[3];
    float* out = (float*)d_out;

    const int B = in_sizes[0] / SEQ;  // 1024

    __hip_bfloat16* P = (__hip_bfloat16*)d_ws;  // 300*512*2 = 307200 B

    proj_kernel<<<dim3(32, 19), 64, 0, stream>>>(emb, Qd, P);
    fused_attn_kernel<<<B, 512, 0, stream>>>(ids_en, ids_fr, emb, P, out);
}

// Round 11
// 168.694 us; speedup vs baseline: 1.2380x; 1.0746x over previous
//
#include <hip/hip_runtime.h>
#include <hip/hip_bf16.h>

#define SEQ 64
#define DIM 512
#define VOCAB 300
#define LDQ 516   // ushort row stride for qkv LDS: 1032B rows (8B-aligned). 8-row quad stride
                  // = 2064 dwords = 16 mod 32 banks -> 2-way aliasing only (free).
                  // Reused in the epilogue as fp32 [32][516] staging (66048 B exactly).
#define LDSC 72   // ushort row stride for scores (144B rows, 16B-aligned)

typedef __attribute__((ext_vector_type(8))) short short8;   // 8 bf16 (MFMA A/B frag)
typedef __attribute__((ext_vector_type(4))) float floatx4;  // MFMA C/D frag; nt-store vector

static __device__ inline unsigned short f2bf(float x) {
    __hip_bfloat16 t = __float2bfloat16(x);
    return *reinterpret_cast<unsigned short*>(&t);
}

// load 8 bf16 from an 8B-aligned LDS address (two uint2 -> ds_read2_b64)
static __device__ inline short8 ld8(const unsigned short* p) {
    union { short8 s; uint2 u[2]; } r;
    r.u[0] = *(const uint2*)p;
    r.u[1] = *(const uint2*)(p + 4);
    return r.s;
}

// async global->LDS, 16B per lane: HW writes LDS at wave-uniform base + lane*16.
static __device__ inline void gload_lds16(const void* g, void* l) {
    __builtin_amdgcn_global_load_lds(
        (const __attribute__((address_space(1))) void*)g,
        (__attribute__((address_space(3))) void*)l, 16, 0, 0);
}

// ---- prep: P = emb @ Qdense (300x512 @ 512x512, bf16 out).
// One 16x16 output tile per WAVE: grid (32 n-tiles) x (19 m-tiles), 64 thr.
__global__ __launch_bounds__(64) void proj_kernel(
    const float* __restrict__ emb,   // fp32 [300][512]
    const float* __restrict__ Q,     // fp32 [512][512], row-major [k][n]
    __hip_bfloat16* __restrict__ P)  // bf16 [300][512]
{
    const int lane = threadIdx.x & 63;
    const int quad = lane >> 4;
    const int l16 = lane & 15;
    const int nt = blockIdx.x;       // 0..31  (column tile)
    const int mt = blockIdx.y;       // 0..18  (row tile; last is partial)
    const int n = nt * 16 + l16;
    const int vrow = mt * 16 + l16;  // A-operand row this lane loads

    floatx4 acc = {};
#pragma unroll 4
    for (int k0 = 0; k0 < DIM; k0 += 32) {
        float4 x0 = {0, 0, 0, 0}, x1 = {0, 0, 0, 0};
        if (vrow < VOCAB) {
            x0 = *(const float4*)(emb + (size_t)vrow * DIM + k0 + quad * 8);
            x1 = *(const float4*)(emb + (size_t)vrow * DIM + k0 + quad * 8 + 4);
        }
        union { short8 s; unsigned short h[8]; } ua;
        ua.h[0] = f2bf(x0.x); ua.h[1] = f2bf(x0.y); ua.h[2] = f2bf(x0.z); ua.h[3] = f2bf(x0.w);
        ua.h[4] = f2bf(x1.x); ua.h[5] = f2bf(x1.y); ua.h[6] = f2bf(x1.z); ua.h[7] = f2bf(x1.w);

        union { short8 s; unsigned short h[8]; } ub;
#pragma unroll
        for (int j = 0; j < 8; j++)
            ub.h[j] = f2bf(Q[(size_t)(k0 + quad * 8 + j) * DIM + n]);

        acc = __builtin_amdgcn_mfma_f32_16x16x32_bf16(ua.s, ub.s, acc, 0, 0, 0);
    }
#pragma unroll
    for (int r = 0; r < 4; r++) {
        int v = mt * 16 + quad * 4 + r;
        if (v < VOCAB) P[(size_t)v * DIM + n] = __float2bfloat16(acc[r]);
    }
}

// ---- main fused kernel: one block per batch, 8 waves, 2 blocks/CU.
// Front: async global_load_lds staging (no VGPR round-trip), scalar ids, 1 barrier.
// Back: Phase C in the R7 (non-transposed) layout + LDS-staged COALESCED epilogue
// (1KB wave stores; R10 showed the direct register epilogue's 64B row-scatter
// costs ~9us in L2 transactions even with plain stores).
__global__ __launch_bounds__(512, 4) void fused_attn_kernel(
    const int* __restrict__ ids_en,
    const int* __restrict__ ids_fr,
    const float* __restrict__ emb,            // fp32 [300][512] (epilogue residual)
    const __hip_bfloat16* __restrict__ P,     // bf16 [300][512] = emb @ W
    float* __restrict__ out)                  // fp32 [B][64][512]
{
    __shared__ __align__(16) unsigned short qk[SEQ * LDQ];   // qkv rows (66048 B); fp32 staging in epilogue
    __shared__ __align__(16) unsigned short sc[SEQ * LDSC];  // scores bf16 (9216 B)
    __shared__ int idsEl[SEQ];

    const int b = blockIdx.x;
    const int tid = threadIdx.x;
    const int lane = tid & 63;
    const int w = tid >> 6;
    const int quad = lane >> 4;
    const int l16 = lane & 15;
    const int n_base = w * 64;
    const int wv = __builtin_amdgcn_readfirstlane(w);  // SGPR wave id

    // idsE -> LDS before barrier 1 (no extra barrier needed)
    if (tid < SEQ) idsEl[tid] = ids_en[b * SEQ + tid];

    // ---- stage qkv = P[ids_fr] into LDS: 8 rows/wave via async global_load_lds.
    // Per row: per-lane global addr P[rid]*DIM + lane*8 ushorts; LDS dest is the
    // wave-uniform row base (HW adds lane*16B) -> linear row, matches layout.
#pragma unroll
    for (int i = 0; i < 8; i++) {
        int rid = ids_fr[b * SEQ + i * 8 + wv];
        gload_lds16(P + (size_t)rid * DIM + lane * 8, qk + (i * 8 + wv) * LDQ);
    }

    // mask values for this wave's two score tiles (overlap with async staging)
    const int t0 = w * 2;
    const int qi = w >> 1;
    const int ki0 = t0 & 3, ki1 = (t0 + 1) & 3;
    float mk0 = (ids_fr[b * SEQ + ki0 * 16 + l16] != 0) ? 1.0f : 0.0f;
    float mk1 = (ids_fr[b * SEQ + ki1 * 16 + l16] != 0) ? 1.0f : 0.0f;

    __syncthreads();  // barrier 1: vmcnt(0) drain completes async staging

    // ---- Phase B: scores = (qkv @ qkv^T) * mask[k]  (16 16x16 tiles, 2/wave, K=512) ----
    short8 bbr[2][4];  // Phase C B-fragments, hoisted (qk bf16 view dead after barrier 2)
    {
        floatx4 accS[2] = {};
        for (int k0 = 0; k0 < DIM; k0 += 32) {
            short8 aa = ld8(qk + (qi * 16 + l16) * LDQ + k0 + quad * 8);
            short8 b0 = ld8(qk + (ki0 * 16 + l16) * LDQ + k0 + quad * 8);
            accS[0] = __builtin_amdgcn_mfma_f32_16x16x32_bf16(aa, b0, accS[0], 0, 0, 0);
            short8 b1 = ld8(qk + (ki1 * 16 + l16) * LDQ + k0 + quad * 8);
            accS[1] = __builtin_amdgcn_mfma_f32_16x16x32_bf16(aa, b1, accS[1], 0, 0, 0);
        }

        // Phase C B-fragment gather (last bf16 reads of qk)
#pragma unroll
        for (int kx = 0; kx < 2; kx++)
#pragma unroll
            for (int ni = 0; ni < 4; ni++)
#pragma unroll
                for (int j = 0; j < 8; j++)
                    ((unsigned short*)&bbr[kx][ni])[j] =
                        qk[(kx * 32 + quad * 8 + j) * LDQ + n_base + ni * 16 + l16];

        // sc writes (masked)
#pragma unroll
        for (int r = 0; r < 4; r++) {
            int row = qi * 16 + quad * 4 + r;
            sc[row * LDSC + ki0 * 16 + l16] = f2bf(accS[0][r] * mk0);
            sc[row * LDSC + ki1 * 16 + l16] = f2bf(accS[1][r] * mk1);
        }
    }
    __syncthreads();  // barrier 2: scores visible

    // ---- Phase C + coalesced epilogue, two passes of 32 rows each ----
    float* const qf = (float*)qk;             // fp32 staging view, stride 516
    const size_t out_base = (size_t)b * SEQ * DIM;
#pragma unroll
    for (int p = 0; p < 2; p++) {
        floatx4 acc[2][4] = {};
#pragma unroll
        for (int kx = 0; kx < 2; kx++) {
            short8 af[2];
#pragma unroll
            for (int mi = 0; mi < 2; mi++)
                af[mi] = *(const short8*)(sc + ((p * 2 + mi) * 16 + l16) * LDSC + kx * 32 + quad * 8);
#pragma unroll
            for (int ni = 0; ni < 4; ni++)
#pragma unroll
                for (int mi = 0; mi < 2; mi++)
                    acc[mi][ni] = __builtin_amdgcn_mfma_f32_16x16x32_bf16(
                        af[mi], bbr[kx][ni], acc[mi][ni], 0, 0, 0);
        }

        if (p == 1) __syncthreads();  // all pass-0 qf reads done before overwrite

        // stage acc -> qf[lr][col] (quad stride 4*516 dwords = 16 mod 32 banks -> free)
#pragma unroll
        for (int mi = 0; mi < 2; mi++)
#pragma unroll
            for (int ni = 0; ni < 4; ni++) {
                int col = n_base + ni * 16 + l16;
#pragma unroll
                for (int r = 0; r < 4; r++)
                    qf[(mi * 16 + quad * 4 + r) * 516 + col] = acc[mi][ni][r];
            }
        __syncthreads();

        // combine + store: thread t, iter j covers flat f = t*4 + j*2048 of the
        // 32x512 tile; row wave-uniform, cols contiguous -> 1KB coalesced accesses.
#pragma unroll
        for (int j = 0; j < 8; j++) {
            int f = tid * 4 + j * 2048;
            int lr = f >> 9;
            int col = f & 511;
            int grow = p * 32 + lr;
            floatx4 v = *(const floatx4*)(qf + lr * 516 + col);
            floatx4 e = *(const floatx4*)(emb + (size_t)idsEl[grow] * DIM + col);
            floatx4 o = e + v;
            __builtin_nontemporal_store(o, (floatx4*)(out + out_base + (size_t)grow * DIM + col));
        }
    }
}

extern "C" void kernel_launch(void* const* d_in, const int* in_sizes, int n_in,
                              void* d_out, int out_size, void* d_ws, size_t ws_size,
                              hipStream_t stream) {
    const int* ids_en = (const int*)d_in[0];
    const int* ids_fr = (const int*)d_in[1];
    const float* emb  = (const float*)d_in[2];
    const float* Qd   = (const float*)d_in[3];
    float* out = (float*)d_out;

    const int B = in_sizes[0] / SEQ;  // 1024

    __hip_bfloat16* P = (__hip_bfloat16*)d_ws;  // 300*512*2 = 307200 B

    proj_kernel<<<dim3(32, 19), 64, 0, stream>>>(emb, Qd, P);
    fused_attn_kernel<<<B, 512, 0, stream>>>(ids_en, ids_fr, emb, P, out);
}